// Round 4
// baseline (769.669 us; speedup 1.0000x reference)
//
#include <hip/hip_runtime.h>

// SparseMinCostFlow — 3-launch: sort_both | flow_chain | scatter_rows.
// N=8192, E=262144, 10 flow iters, dense NxN fp32 out (256 MB).
//
// r3 post-mortem: chain stage cost (~18us) invariant under traffic changes
// (2MB -> 96KB -> ~0 per stage) => sync-structure-bound, unattributable
// inside the fused mega-kernel. This round:
//  K1 sort_both   (64 blk): col-sort (32 buckets, for chain) + row-sort
//                 (256 groups, for output), independent teams.
//  K2 flow_chain  (8 blk): 9 stages; 32 edges/thread in regs; 1024 cols/blk;
//                 8-participant flag barrier. CLEAN-ROOM chain measurement.
//  K3 scatter_rows(256 blk): per 32-row group: LDS row image (zero + add
//                 premultiplied edges + float4 stream). Output written ONCE:
//                 no 256MB pre-zero, no global atomics.
// Cross-kernel visibility via dispatch boundaries (no flags between kernels).

#define NN 8192
#define EE 262144
#define THREADS 1024
#define CSB 32                   // col-sort blocks / col buckets
#define RSB 32                   // row-sort blocks
#define EPB (EE / CSB)           // 8192 edges per sort block
#define CBLK 8                   // chain blocks
#define CCOLS (NN / CBLK)        // 1024 cols per chain block
#define EREG 36                  // edge slots/thread in K2 (32768/1024 + slack)
#define NGRP 256                 // row groups
#define GROWS (NN / NGRP)        // 32 rows per group
#define HN (NN / 2)              // u64 words per adj vector
#define MAGIC 0x5CA1AB1Eu        // != 0xAAAAAAAA ws poison, != 0

typedef unsigned long long u64;

#define LOAD_AU(p)    __hip_atomic_load((p),  __ATOMIC_RELAXED, __HIP_MEMORY_SCOPE_AGENT)
#define STORE_AU(p,v) __hip_atomic_store((p), (v), __ATOMIC_RELAXED, __HIP_MEMORY_SCOPE_AGENT)

// Team barrier: own-word flag store + one polling wave. Caller must
// __syncthreads() first (s_waitcnt vmcnt(0): data ahead of flag).
__device__ __forceinline__ void flag_barrier_n(unsigned* fl, int idx, int tid, int nblk) {
    if (tid == 0) STORE_AU(&fl[idx], MAGIC);
    asm volatile("" ::: "memory");
    if (tid < 64) {
        for (;;) {
            unsigned f = (tid < nblk) ? LOAD_AU(&fl[tid]) : MAGIC;
            if (__all(f == MAGIC)) break;
            __builtin_amdgcn_s_sleep(2);
        }
    }
    asm volatile("" ::: "memory");
    __syncthreads();
}

// ============================ K1: both sorts ============================
__global__ void __launch_bounds__(THREADS) sort_both(
        const float* __restrict__ values,
        const int* __restrict__ rows, const int* __restrict__ cols,
        u64* __restrict__ se,        // EE col-sorted: (row13|coff8<<13)|v<<32
        u64* __restrict__ se2,       // EE row-sorted: (col13|rl5<<13)|v<<32
        unsigned* __restrict__ cnt,  // CSB*CSB
        unsigned* __restrict__ cnt2, // RSB*NGRP
        unsigned* __restrict__ bstart,   // CSB+1
        unsigned* __restrict__ gstart,   // NGRP+1
        unsigned* __restrict__ flagsC, unsigned* __restrict__ flagsR) {
    __shared__ unsigned cntL[RSB * NGRP];    // 32 KB (col team uses first 1024)
    __shared__ unsigned histL[NGRP];
    __shared__ unsigned bstL[NGRP + 1];
    __shared__ unsigned offsL[NGRP];
    const int bid = blockIdx.x, tid = threadIdx.x;

    if (bid < CSB) {
        // ---------------- col-sort team: bucket = col>>8 ----------------
        if (tid < CSB) histL[tid] = 0;
        __syncthreads();
        const int4* c4 = (const int4*)(cols + bid * EPB);
        int4 ca = c4[2 * tid], cb = c4[2 * tid + 1];
        atomicAdd(&histL[ca.x >> 8], 1u);  atomicAdd(&histL[ca.y >> 8], 1u);
        atomicAdd(&histL[ca.z >> 8], 1u);  atomicAdd(&histL[ca.w >> 8], 1u);
        atomicAdd(&histL[cb.x >> 8], 1u);  atomicAdd(&histL[cb.y >> 8], 1u);
        atomicAdd(&histL[cb.z >> 8], 1u);  atomicAdd(&histL[cb.w >> 8], 1u);
        __syncthreads();
        if (tid < CSB) STORE_AU(&cnt[bid * CSB + tid], histL[tid]);
        __syncthreads();
        flag_barrier_n(flagsC, bid, tid, CSB);

        cntL[tid] = LOAD_AU(&cnt[tid]);              // CSB*CSB == THREADS
        __syncthreads();
        if (tid < CSB) {
            unsigned t = 0;
            for (int b = 0; b < CSB; ++b) t += cntL[b * CSB + tid];
            histL[tid] = t;
        }
        __syncthreads();
        if (tid == 0) {
            unsigned run = 0;
            for (int k = 0; k < CSB; ++k) { bstL[k] = run; run += histL[k]; }
            bstL[CSB] = run;
        }
        __syncthreads();
        if (tid < CSB) {
            unsigned off = bstL[tid];
            for (int b = 0; b < bid; ++b) off += cntL[b * CSB + tid];
            offsL[tid] = off;
        }
        __syncthreads();
        if (bid == 0 && tid <= CSB) bstart[tid] = bstL[tid];   // for K2

        const int4*   r4 = (const int4*)(rows + bid * EPB);
        const float4* v4 = (const float4*)(values + bid * EPB);
        int4 ra = r4[2 * tid], rb = r4[2 * tid + 1];
        float4 va = v4[2 * tid], vb = v4[2 * tid + 1];
        #define PUSHC(R, C, V) do {                                            \
            int k_ = (C) >> 8;                                                 \
            unsigned dst_ = atomicAdd(&offsL[k_], 1u);                         \
            u64 w_ = (unsigned)((R) | (((C) & 255) << 13))                     \
                   | ((u64)__float_as_uint(V) << 32);                          \
            STORE_AU(&se[dst_], w_);                                           \
        } while (0)
        PUSHC(ra.x, ca.x, va.x);  PUSHC(ra.y, ca.y, va.y);
        PUSHC(ra.z, ca.z, va.z);  PUSHC(ra.w, ca.w, va.w);
        PUSHC(rb.x, cb.x, vb.x);  PUSHC(rb.y, cb.y, vb.y);
        PUSHC(rb.z, cb.z, vb.z);  PUSHC(rb.w, cb.w, vb.w);
        #undef PUSHC
    } else {
        // ---------------- row-sort team: group = row>>5 ----------------
        const int b2 = bid - CSB;
        if (tid < NGRP) histL[tid] = 0;
        __syncthreads();
        const int4* r4 = (const int4*)(rows + b2 * EPB);
        int4 ra = r4[2 * tid], rb = r4[2 * tid + 1];
        atomicAdd(&histL[ra.x >> 5], 1u);  atomicAdd(&histL[ra.y >> 5], 1u);
        atomicAdd(&histL[ra.z >> 5], 1u);  atomicAdd(&histL[ra.w >> 5], 1u);
        atomicAdd(&histL[rb.x >> 5], 1u);  atomicAdd(&histL[rb.y >> 5], 1u);
        atomicAdd(&histL[rb.z >> 5], 1u);  atomicAdd(&histL[rb.w >> 5], 1u);
        __syncthreads();
        if (tid < NGRP) STORE_AU(&cnt2[b2 * NGRP + tid], histL[tid]);
        __syncthreads();
        flag_barrier_n(flagsR, b2, tid, RSB);

        #pragma unroll
        for (int j = 0; j < (RSB * NGRP) / THREADS; ++j)
            cntL[tid + j * THREADS] = LOAD_AU(&cnt2[tid + j * THREADS]);
        __syncthreads();
        if (tid < NGRP) {
            unsigned t = 0;
            for (int b = 0; b < RSB; ++b) t += cntL[b * NGRP + tid];
            histL[tid] = t;
        }
        __syncthreads();
        if (tid == 0) {
            unsigned run = 0;
            for (int k = 0; k < NGRP; ++k) { bstL[k] = run; run += histL[k]; }
            bstL[NGRP] = run;
        }
        __syncthreads();
        if (tid < NGRP) {
            unsigned off = bstL[tid];
            for (int b = 0; b < b2; ++b) off += cntL[b * NGRP + tid];
            offsL[tid] = off;
        }
        __syncthreads();
        if (b2 == 0 && tid <= NGRP) gstart[tid] = bstL[tid];   // for K3

        const int4*   c4 = (const int4*)(cols + b2 * EPB);
        const float4* v4 = (const float4*)(values + b2 * EPB);
        int4 ca = c4[2 * tid], cb = c4[2 * tid + 1];
        float4 va = v4[2 * tid], vb = v4[2 * tid + 1];
        #define PUSHR(R, C, V) do {                                            \
            int g_ = (R) >> 5;                                                 \
            unsigned dst_ = atomicAdd(&offsL[g_], 1u);                         \
            u64 w_ = (unsigned)((C) | (((R) & 31) << 13))                      \
                   | ((u64)__float_as_uint(V) << 32);                          \
            STORE_AU(&se2[dst_], w_);                                          \
        } while (0)
        PUSHR(ra.x, ca.x, va.x);  PUSHR(ra.y, ca.y, va.y);
        PUSHR(ra.z, ca.z, va.z);  PUSHR(ra.w, ca.w, va.w);
        PUSHR(rb.x, cb.x, vb.x);  PUSHR(rb.y, cb.y, vb.y);
        PUSHR(rb.z, cb.z, vb.z);  PUSHR(rb.w, cb.w, vb.w);
        #undef PUSHR
    }
}

// ============================ K2: flow chain ============================
__global__ void __launch_bounds__(THREADS, 4) flow_chain(
        const float* __restrict__ dem,
        const u64* __restrict__ se,          // col-sorted (dispatch-visible)
        const unsigned* __restrict__ bstart, // CSB+1 bucket starts
        u64* __restrict__ adjp,              // 9*HN (slots 1..8)
        float* __restrict__ adj9f,           // NN (= A10)
        unsigned* __restrict__ flagsK) {
    __shared__ float adjLDS[NN];             // 32 KB
    __shared__ float accLDS[CCOLS];
    __shared__ float demLDS[CCOLS];
    const int bid = blockIdx.x, tid = threadIdx.x;

    const int b0 = (int)bstart[4 * bid];
    const int b1 = (int)bstart[4 * bid + 1];
    const int b2 = (int)bstart[4 * bid + 2];
    const int b3 = (int)bstart[4 * bid + 3];
    const int b4 = (int)bstart[4 * bid + 4];

    // preload my ~32768 edges: meta = clocal10<<13 | row13, value separate
    unsigned em[EREG]; float ev[EREG];
    #pragma unroll
    for (int j = 0; j < EREG; ++j) {
        int i = b0 + tid + j * THREADS;
        if (i < b4) {
            u64 w = se[i];
            unsigned m = (unsigned)w;
            int k = (i >= b1) + (i >= b2) + (i >= b3);
            em[j] = (unsigned)(((k << 8) + ((m >> 13) & 255)) << 13) | (m & (NN - 1));
            ev[j] = __uint_as_float((unsigned)(w >> 32));
        } else { em[j] = 0; ev[j] = 0.f; }
    }
    demLDS[tid] = dem[bid * CCOLS + tid];

    for (int s = 1; s <= 9; ++s) {
        if (s == 1) {
            #pragma unroll
            for (int j = 0; j < NN / THREADS; ++j) {
                int c = tid + j * THREADS;
                adjLDS[c] = fmaxf(-dem[c], 0.f);            // A1
            }
        } else {
            const u64* ap = adjp + (size_t)(s - 1) * HN;
            #pragma unroll
            for (int j = 0; j < HN / THREADS; ++j) {
                int i = tid + j * THREADS;
                u64 w = LOAD_AU(&ap[i]);
                adjLDS[2 * i]     = __uint_as_float((unsigned)w);
                adjLDS[2 * i + 1] = __uint_as_float((unsigned)(w >> 32));
            }
        }
        accLDS[tid] = 0.f;
        __syncthreads();

        #pragma unroll
        for (int j = 0; j < EREG; ++j)
            atomicAdd(&accLDS[em[j] >> 13], ev[j] * adjLDS[em[j] & (NN - 1)]);
        for (int i = b0 + EREG * THREADS + tid; i < b4; i += THREADS) { // ~never
            u64 w = se[i];
            unsigned m = (unsigned)w;
            int k = (i >= b1) + (i >= b2) + (i >= b3);
            int cl = (k << 8) + ((m >> 13) & 255);
            atomicAdd(&accLDS[cl], __uint_as_float((unsigned)(w >> 32))
                                   * adjLDS[m & (NN - 1)]);
        }
        __syncthreads();

        if (s < 9) {
            if (tid < CCOLS / 2) {            // fused relu + pack + publish 4KB
                float lo = fmaxf(accLDS[2 * tid]     - demLDS[2 * tid],     0.f);
                float hi = fmaxf(accLDS[2 * tid + 1] - demLDS[2 * tid + 1], 0.f);
                u64 w = ((u64)__float_as_uint(hi) << 32) | __float_as_uint(lo);
                STORE_AU(&adjp[(size_t)s * HN + bid * (CCOLS / 2) + tid], w);
            }
            __syncthreads();                  // drain publish
            flag_barrier_n(flagsK + (s - 1) * 64, bid, tid, CBLK);
        } else {
            adj9f[bid * CCOLS + tid] = fmaxf(accLDS[tid] - demLDS[tid], 0.f);
            // dispatch boundary publishes adj9f for K3
        }
    }
}

// ========================= K3: row-streamed output =========================
__global__ void __launch_bounds__(THREADS) scatter_rows(
        const u64* __restrict__ se2, const unsigned* __restrict__ gstart,
        const float* __restrict__ adj9f, float* __restrict__ out) {
    __shared__ float img[NN];                // 32 KB row image
    __shared__ u64  eL[2048];                // 16 KB premultiplied group edges
    const int g = blockIdx.x, tid = threadIdx.x;
    const unsigned gs = gstart[g], ge = gstart[g + 1];
    const unsigned n = ge - gs;
    const unsigned nc = n < 2048u ? n : 2048u;

    for (unsigned i = tid; i < nc; i += THREADS) {    // premultiply by adj9[row]
        u64 w = se2[gs + i];
        unsigned m = (unsigned)w;
        float v = __uint_as_float((unsigned)(w >> 32));
        float a = adj9f[g * GROWS + ((m >> 13) & 31)];
        eL[i] = (u64)m | ((u64)__float_as_uint(v * a) << 32);
    }
    __syncthreads();

    for (int r = 0; r < GROWS; ++r) {
        #pragma unroll
        for (int k = 0; k < NN / THREADS; ++k) img[tid + k * THREADS] = 0.f;
        __syncthreads();
        for (unsigned i = tid; i < nc; i += THREADS) {
            u64 w = eL[i];
            unsigned m = (unsigned)w;
            if (((m >> 13) & 31) == (unsigned)r)
                atomicAdd(&img[m & (NN - 1)], __uint_as_float((unsigned)(w >> 32)));
        }
        for (unsigned i = 2048u + tid; i < n; i += THREADS) {  // ~never
            u64 w = se2[gs + i];
            unsigned m = (unsigned)w;
            if (((m >> 13) & 31) == (unsigned)r) {
                float v = __uint_as_float((unsigned)(w >> 32));
                atomicAdd(&img[m & (NN - 1)], v * adj9f[g * GROWS + r]);
            }
        }
        __syncthreads();
        float4* o4 = (float4*)(out + (size_t)(g * GROWS + r) * NN);
        const float4* i4 = (const float4*)img;
        o4[tid]        = i4[tid];
        o4[tid + 1024] = i4[tid + 1024];
        __syncthreads();
    }
}

extern "C" void kernel_launch(void* const* d_in, const int* in_sizes, int n_in,
                              void* d_out, int out_size, void* d_ws, size_t ws_size,
                              hipStream_t stream) {
    const float* values = (const float*)d_in[0];
    const float* dem    = (const float*)d_in[1];
    const int*   rows   = (const int*)d_in[2];
    const int*   cols   = (const int*)d_in[3];
    float* out = (float*)d_out;

    u64*      se     = (u64*)d_ws;                        // 2 MB
    u64*      se2    = se + (size_t)EE;                   // 2 MB
    u64*      adjp   = se2 + (size_t)EE;                  // 288 KB
    float*    adj9f  = (float*)(adjp + 9L * HN);          // 32 KB
    unsigned* cnt    = (unsigned*)(adj9f + NN);           // 4 KB
    unsigned* cnt2   = cnt + CSB * CSB;                   // 32 KB
    unsigned* bstart = cnt2 + RSB * NGRP;                 // 132 B
    unsigned* gstart = bstart + (CSB + 1);                // 1 KB
    unsigned* flagsC = gstart + (NGRP + 1);               // 256 B
    unsigned* flagsR = flagsC + 64;                       // 256 B
    unsigned* flagsK = flagsR + 64;                       // 2 KB

    sort_both<<<CSB + RSB, THREADS, 0, stream>>>(
        values, rows, cols, se, se2, cnt, cnt2, bstart, gstart, flagsC, flagsR);

    flow_chain<<<CBLK, THREADS, 0, stream>>>(
        dem, se, bstart, adjp, adj9f, flagsK);

    scatter_rows<<<NGRP, THREADS, 0, stream>>>(
        se2, gstart, adj9f, out);
}

// Round 5
// 412.707 us; speedup vs baseline: 1.8649x; 1.8649x over previous
//
#include <hip/hip_runtime.h>

// SparseMinCostFlow — 3-launch: sort_both | flow_chain (LDS edges) | scatter_rows.
// N=8192, E=262144, 10 flow iters, dense NxN fp32 out (256 MB).
//
// r4 post-mortem: "edges in registers" spilled to scratch (VGPR_Count=64 <
// 72 needed) => every prior chain streamed edges at ~200cyc latency each
// stage (MALL in r2, scratch in r3/r4). That, not the barrier, is the
// ~18-54us/stage cost. Fix: edges live in LDS (~6cyc).
//  K1 sort_both   (64 blk): col-sort (32 buckets) + row-sort (256 groups).
//  K2 flow_chain  (32 blk): bucket's ~8192 edges -> 64KB LDS once; per stage:
//                 adj 32KB reload + LDS edge pass + 1KB publish + flag barrier.
//                 NO register arrays (rule #20), no per-stage global edge reads.
//  K3 scatter_rows(256 blk): per 32-row group: LDS row image -> float4 stream.
//                 Output written ONCE: no 256MB pre-zero, no global atomics.
// Cross-kernel visibility via dispatch boundaries.

#define NN 8192
#define EE 262144
#define THREADS 1024
#define CSB 32                   // col-sort blocks / col buckets
#define RSB 32                   // row-sort blocks
#define EPB (EE / CSB)           // 8192 edges per sort block
#define FBLK 32                  // chain blocks (1 bucket each)
#define SLICE (NN / FBLK)        // 256 cols owned per chain block
#define HSLICE (SLICE / 2)
#define ECAP 9216                // LDS edge capacity (mean 8192, sd ~89)
#define NGRP 256                 // row groups
#define GROWS (NN / NGRP)        // 32 rows per group
#define HN (NN / 2)              // u64 words per adj vector
#define MAGIC 0x5CA1AB1Eu        // != 0xAAAAAAAA ws poison, != 0

typedef unsigned long long u64;

#define LOAD_AU(p)    __hip_atomic_load((p),  __ATOMIC_RELAXED, __HIP_MEMORY_SCOPE_AGENT)
#define STORE_AU(p,v) __hip_atomic_store((p), (v), __ATOMIC_RELAXED, __HIP_MEMORY_SCOPE_AGENT)

// Team barrier: own-word flag store + one polling wave. Caller must
// __syncthreads() first (s_waitcnt vmcnt(0): data ahead of flag).
__device__ __forceinline__ void flag_barrier_n(unsigned* fl, int idx, int tid, int nblk) {
    if (tid == 0) STORE_AU(&fl[idx], MAGIC);
    asm volatile("" ::: "memory");
    if (tid < 64) {
        for (;;) {
            unsigned f = (tid < nblk) ? LOAD_AU(&fl[tid]) : MAGIC;
            if (__all(f == MAGIC)) break;
            __builtin_amdgcn_s_sleep(2);
        }
    }
    asm volatile("" ::: "memory");
    __syncthreads();
}

// ============================ K1: both sorts ============================
__global__ void __launch_bounds__(THREADS) sort_both(
        const float* __restrict__ values,
        const int* __restrict__ rows, const int* __restrict__ cols,
        u64* __restrict__ se,        // EE col-sorted: (row13|coff8<<13)|v<<32
        u64* __restrict__ se2,       // EE row-sorted: (col13|rl5<<13)|v<<32
        unsigned* __restrict__ cnt,  // CSB*CSB
        unsigned* __restrict__ cnt2, // RSB*NGRP
        unsigned* __restrict__ bstart,   // CSB+1
        unsigned* __restrict__ gstart,   // NGRP+1
        unsigned* __restrict__ flagsC, unsigned* __restrict__ flagsR) {
    __shared__ unsigned cntL[RSB * NGRP];    // 32 KB (col team uses first 1024)
    __shared__ unsigned histL[NGRP];
    __shared__ unsigned bstL[NGRP + 1];
    __shared__ unsigned offsL[NGRP];
    const int bid = blockIdx.x, tid = threadIdx.x;

    if (bid < CSB) {
        // ---------------- col-sort team: bucket = col>>8 ----------------
        if (tid < CSB) histL[tid] = 0;
        __syncthreads();
        const int4* c4 = (const int4*)(cols + bid * EPB);
        int4 ca = c4[2 * tid], cb = c4[2 * tid + 1];
        atomicAdd(&histL[ca.x >> 8], 1u);  atomicAdd(&histL[ca.y >> 8], 1u);
        atomicAdd(&histL[ca.z >> 8], 1u);  atomicAdd(&histL[ca.w >> 8], 1u);
        atomicAdd(&histL[cb.x >> 8], 1u);  atomicAdd(&histL[cb.y >> 8], 1u);
        atomicAdd(&histL[cb.z >> 8], 1u);  atomicAdd(&histL[cb.w >> 8], 1u);
        __syncthreads();
        if (tid < CSB) STORE_AU(&cnt[bid * CSB + tid], histL[tid]);
        __syncthreads();
        flag_barrier_n(flagsC, bid, tid, CSB);

        cntL[tid] = LOAD_AU(&cnt[tid]);              // CSB*CSB == THREADS
        __syncthreads();
        if (tid < CSB) {
            unsigned t = 0;
            for (int b = 0; b < CSB; ++b) t += cntL[b * CSB + tid];
            histL[tid] = t;
        }
        __syncthreads();
        if (tid == 0) {
            unsigned run = 0;
            for (int k = 0; k < CSB; ++k) { bstL[k] = run; run += histL[k]; }
            bstL[CSB] = run;
        }
        __syncthreads();
        if (tid < CSB) {
            unsigned off = bstL[tid];
            for (int b = 0; b < bid; ++b) off += cntL[b * CSB + tid];
            offsL[tid] = off;
        }
        __syncthreads();
        if (bid == 0 && tid <= CSB) bstart[tid] = bstL[tid];   // for K2

        const int4*   r4 = (const int4*)(rows + bid * EPB);
        const float4* v4 = (const float4*)(values + bid * EPB);
        int4 ra = r4[2 * tid], rb = r4[2 * tid + 1];
        float4 va = v4[2 * tid], vb = v4[2 * tid + 1];
        #define PUSHC(R, C, V) do {                                            \
            int k_ = (C) >> 8;                                                 \
            unsigned dst_ = atomicAdd(&offsL[k_], 1u);                         \
            u64 w_ = (unsigned)((R) | (((C) & 255) << 13))                     \
                   | ((u64)__float_as_uint(V) << 32);                          \
            STORE_AU(&se[dst_], w_);                                           \
        } while (0)
        PUSHC(ra.x, ca.x, va.x);  PUSHC(ra.y, ca.y, va.y);
        PUSHC(ra.z, ca.z, va.z);  PUSHC(ra.w, ca.w, va.w);
        PUSHC(rb.x, cb.x, vb.x);  PUSHC(rb.y, cb.y, vb.y);
        PUSHC(rb.z, cb.z, vb.z);  PUSHC(rb.w, cb.w, vb.w);
        #undef PUSHC
    } else {
        // ---------------- row-sort team: group = row>>5 ----------------
        const int b2 = bid - CSB;
        if (tid < NGRP) histL[tid] = 0;
        __syncthreads();
        const int4* r4 = (const int4*)(rows + b2 * EPB);
        int4 ra = r4[2 * tid], rb = r4[2 * tid + 1];
        atomicAdd(&histL[ra.x >> 5], 1u);  atomicAdd(&histL[ra.y >> 5], 1u);
        atomicAdd(&histL[ra.z >> 5], 1u);  atomicAdd(&histL[ra.w >> 5], 1u);
        atomicAdd(&histL[rb.x >> 5], 1u);  atomicAdd(&histL[rb.y >> 5], 1u);
        atomicAdd(&histL[rb.z >> 5], 1u);  atomicAdd(&histL[rb.w >> 5], 1u);
        __syncthreads();
        if (tid < NGRP) STORE_AU(&cnt2[b2 * NGRP + tid], histL[tid]);
        __syncthreads();
        flag_barrier_n(flagsR, b2, tid, RSB);

        #pragma unroll
        for (int j = 0; j < (RSB * NGRP) / THREADS; ++j)
            cntL[tid + j * THREADS] = LOAD_AU(&cnt2[tid + j * THREADS]);
        __syncthreads();
        if (tid < NGRP) {
            unsigned t = 0;
            for (int b = 0; b < RSB; ++b) t += cntL[b * NGRP + tid];
            histL[tid] = t;
        }
        __syncthreads();
        if (tid == 0) {
            unsigned run = 0;
            for (int k = 0; k < NGRP; ++k) { bstL[k] = run; run += histL[k]; }
            bstL[NGRP] = run;
        }
        __syncthreads();
        if (tid < NGRP) {
            unsigned off = bstL[tid];
            for (int b = 0; b < b2; ++b) off += cntL[b * NGRP + tid];
            offsL[tid] = off;
        }
        __syncthreads();
        if (b2 == 0 && tid <= NGRP) gstart[tid] = bstL[tid];   // for K3

        const int4*   c4 = (const int4*)(cols + b2 * EPB);
        const float4* v4 = (const float4*)(values + b2 * EPB);
        int4 ca = c4[2 * tid], cb = c4[2 * tid + 1];
        float4 va = v4[2 * tid], vb = v4[2 * tid + 1];
        #define PUSHR(R, C, V) do {                                            \
            int g_ = (R) >> 5;                                                 \
            unsigned dst_ = atomicAdd(&offsL[g_], 1u);                         \
            u64 w_ = (unsigned)((C) | (((R) & 31) << 13))                      \
                   | ((u64)__float_as_uint(V) << 32);                          \
            STORE_AU(&se2[dst_], w_);                                          \
        } while (0)
        PUSHR(ra.x, ca.x, va.x);  PUSHR(ra.y, ca.y, va.y);
        PUSHR(ra.z, ca.z, va.z);  PUSHR(ra.w, ca.w, va.w);
        PUSHR(rb.x, cb.x, vb.x);  PUSHR(rb.y, cb.y, vb.y);
        PUSHR(rb.z, cb.z, vb.z);  PUSHR(rb.w, cb.w, vb.w);
        #undef PUSHR
    }
}

// ==================== K2: flow chain, edges in LDS ====================
__global__ void __launch_bounds__(THREADS) flow_chain(
        const float* __restrict__ dem,
        const u64* __restrict__ se,          // col-sorted (dispatch-visible)
        const unsigned* __restrict__ bstart, // CSB+1 bucket starts
        u64* __restrict__ adjp,              // 9*HN (slots 1..8)
        float* __restrict__ adj9f,           // NN (= A10)
        unsigned* __restrict__ flagsK) {
    __shared__ float adjLDS[NN];             // 32 KB
    __shared__ u64   eLDS[ECAP];             // 72 KB
    __shared__ float accLDS[SLICE];          // 1 KB
    __shared__ float demLDS[SLICE];          // 1 KB   => ~106 KB, 1 blk/CU
    const int bid = blockIdx.x, tid = threadIdx.x;

    const int bs = (int)bstart[bid];
    const int be = (int)bstart[bid + 1];
    const int ne = be - bs;
    const int nc = ne < ECAP ? ne : ECAP;

    // bucket's edges -> LDS, once (64 KB; ~6cyc/elem thereafter, no spill)
    for (int i = tid; i < nc; i += THREADS) eLDS[i] = se[bs + i];
    if (tid < SLICE) demLDS[tid] = dem[bid * SLICE + tid];

    for (int s = 1; s <= 9; ++s) {
        if (s == 1) {                         // A1 = relu(0 - d)
            #pragma unroll
            for (int j = 0; j < NN / THREADS; ++j) {
                int c = tid + j * THREADS;
                adjLDS[c] = fmaxf(-dem[c], 0.f);
            }
        } else {                              // A_s published at stage s-1
            const u64* ap = adjp + (size_t)(s - 1) * HN;
            #pragma unroll
            for (int j = 0; j < HN / THREADS; ++j) {
                int i = tid + j * THREADS;
                u64 w = LOAD_AU(&ap[i]);
                adjLDS[2 * i]     = __uint_as_float((unsigned)w);
                adjLDS[2 * i + 1] = __uint_as_float((unsigned)(w >> 32));
            }
        }
        if (tid < SLICE) accLDS[tid] = 0.f;
        __syncthreads();                      // also covers eLDS/demLDS @ s=1

        // edge pass: pure-LDS (read b64 + ds_add_f32)
        for (int i = tid; i < nc; i += THREADS) {
            u64 w = eLDS[i];
            unsigned m = (unsigned)w;
            float v = __uint_as_float((unsigned)(w >> 32));
            atomicAdd(&accLDS[(m >> 13) & 255], v * adjLDS[m & (NN - 1)]);
        }
        for (int i = bs + ECAP + tid; i < be; i += THREADS) {   // ~never
            u64 w = LOAD_AU(&se[i]);
            unsigned m = (unsigned)w;
            float v = __uint_as_float((unsigned)(w >> 32));
            atomicAdd(&accLDS[(m >> 13) & 255], v * adjLDS[m & (NN - 1)]);
        }
        __syncthreads();

        if (s < 9) {
            if (tid < HSLICE) {               // fused relu + pack + publish 1KB
                float lo = fmaxf(accLDS[2 * tid]     - demLDS[2 * tid],     0.f);
                float hi = fmaxf(accLDS[2 * tid + 1] - demLDS[2 * tid + 1], 0.f);
                u64 w = ((u64)__float_as_uint(hi) << 32) | __float_as_uint(lo);
                STORE_AU(&adjp[(size_t)s * HN + bid * HSLICE + tid], w);
            }
            __syncthreads();                  // drain publish
            flag_barrier_n(flagsK + (s - 1) * 64, bid, tid, FBLK);
        } else {
            if (tid < SLICE)
                adj9f[bid * SLICE + tid] = fmaxf(accLDS[tid] - demLDS[tid], 0.f);
            // dispatch boundary publishes adj9f for K3
        }
    }
}

// ========================= K3: row-streamed output =========================
__global__ void __launch_bounds__(THREADS) scatter_rows(
        const u64* __restrict__ se2, const unsigned* __restrict__ gstart,
        const float* __restrict__ adj9f, float* __restrict__ out) {
    __shared__ float img[NN];                // 32 KB row image
    __shared__ u64  eL[2048];                // 16 KB premultiplied group edges
    const int g = blockIdx.x, tid = threadIdx.x;
    const unsigned gs = gstart[g], ge = gstart[g + 1];
    const unsigned n = ge - gs;
    const unsigned nc = n < 2048u ? n : 2048u;

    for (unsigned i = tid; i < nc; i += THREADS) {    // premultiply by adj9[row]
        u64 w = se2[gs + i];
        unsigned m = (unsigned)w;
        float v = __uint_as_float((unsigned)(w >> 32));
        float a = adj9f[g * GROWS + ((m >> 13) & 31)];
        eL[i] = (u64)m | ((u64)__float_as_uint(v * a) << 32);
    }
    __syncthreads();

    for (int r = 0; r < GROWS; ++r) {
        #pragma unroll
        for (int k = 0; k < NN / THREADS; ++k) img[tid + k * THREADS] = 0.f;
        __syncthreads();
        for (unsigned i = tid; i < nc; i += THREADS) {
            u64 w = eL[i];
            unsigned m = (unsigned)w;
            if (((m >> 13) & 31) == (unsigned)r)
                atomicAdd(&img[m & (NN - 1)], __uint_as_float((unsigned)(w >> 32)));
        }
        for (unsigned i = 2048u + tid; i < n; i += THREADS) {  // ~never
            u64 w = se2[gs + i];
            unsigned m = (unsigned)w;
            if (((m >> 13) & 31) == (unsigned)r) {
                float v = __uint_as_float((unsigned)(w >> 32));
                atomicAdd(&img[m & (NN - 1)], v * adj9f[g * GROWS + r]);
            }
        }
        __syncthreads();
        float4* o4 = (float4*)(out + (size_t)(g * GROWS + r) * NN);
        const float4* i4 = (const float4*)img;
        o4[tid]        = i4[tid];
        o4[tid + 1024] = i4[tid + 1024];
        __syncthreads();
    }
}

extern "C" void kernel_launch(void* const* d_in, const int* in_sizes, int n_in,
                              void* d_out, int out_size, void* d_ws, size_t ws_size,
                              hipStream_t stream) {
    const float* values = (const float*)d_in[0];
    const float* dem    = (const float*)d_in[1];
    const int*   rows   = (const int*)d_in[2];
    const int*   cols   = (const int*)d_in[3];
    float* out = (float*)d_out;

    u64*      se     = (u64*)d_ws;                        // 2 MB
    u64*      se2    = se + (size_t)EE;                   // 2 MB
    u64*      adjp   = se2 + (size_t)EE;                  // 288 KB
    float*    adj9f  = (float*)(adjp + 9L * HN);          // 32 KB
    unsigned* cnt    = (unsigned*)(adj9f + NN);           // 4 KB
    unsigned* cnt2   = cnt + CSB * CSB;                   // 32 KB
    unsigned* bstart = cnt2 + RSB * NGRP;                 // 132 B
    unsigned* gstart = bstart + (CSB + 1);                // 1 KB
    unsigned* flagsC = gstart + (NGRP + 1);               // 256 B
    unsigned* flagsR = flagsC + 64;                       // 256 B
    unsigned* flagsK = flagsR + 64;                       // 2 KB

    sort_both<<<CSB + RSB, THREADS, 0, stream>>>(
        values, rows, cols, se, se2, cnt, cnt2, bstart, gstart, flagsC, flagsR);

    flow_chain<<<FBLK, THREADS, 0, stream>>>(
        dem, se, bstart, adjp, adj9f, flagsK);

    scatter_rows<<<NGRP, THREADS, 0, stream>>>(
        se2, gstart, adj9f, out);
}

// Round 8
// 403.271 us; speedup vs baseline: 1.9086x; 1.0234x over previous
//
#include <hip/hip_runtime.h>

// SparseMinCostFlow — SINGLE mega-dispatch: sorts ∥ chain → scatter.
// N=8192, E=262144, 10 flow iters, dense NxN fp32 out (256 MB).
//
// r5: LDS-edge chain fixed the r4 scratch-spill; all top-5 dispatches became
// the harness's 1-GiB ws-poison fill (~162us/iter, fixed cost).
// r6/r7: fuse sort|chain|scatter into ONE kernel (256 blocks, 1/CU, 108KB LDS).
// r8 fix (tripwire race): pre-scatter precondition now UNIFORM — every block
// observes all 32 flagsR2 AND all 32 done before touching se2/gstart/adj9f.
// (r7 bug: chain blocks scattered group bid using adj9f owned by block bid/8
// without waiting on other chain blocks' done; row-sort blocks skipped the
// flagsR2-all wait. Timing-dependent => graph vs launch_once divergence.)
//
//   blocks 0..31 : col-sort -> flagE barrier -> chain (edges in LDS, 8 flag
//                  barriers) -> publish adj9f + done BARRIER -> scatter
//   blocks 32..63: row-sort -> set flagsR2 -> wait R2all+doneall -> scatter
//   blocks 64..255: sleep-poll R2all+doneall -> scatter
// All cross-block traffic agent-scope; flags set after __syncthreads (vmcnt
// drain). MAGIC != 0xAA poison => no ws init needed. Grid=256=#CUs, 1 blk/CU,
// prerequisite blocks (0..63) dispatched first => no deadlock.

#define NN 8192
#define EE 262144
#define THREADS 1024
#define CSB 32                   // col-sort blocks / col buckets
#define RSB 32                   // row-sort blocks
#define EPB (EE / CSB)           // 8192 edges per sort block
#define FBLK 32                  // chain blocks (= col-sort blocks)
#define SLICE (NN / FBLK)        // 256 cols owned per chain block
#define HSLICE (SLICE / 2)
#define ECAP 9216                // LDS edge capacity (mean 8192, sd ~89)
#define NGRP 256                 // row groups (1 per block)
#define GROWS (NN / NGRP)        // 32 rows per group
#define HN (NN / 2)              // u64 words per adj vector
#define NBLK 256
#define MAGIC 0x5CA1AB1Eu        // != 0xAAAAAAAA ws poison, != 0

typedef unsigned long long u64;

#define LOAD_AU(p)    __hip_atomic_load((p),  __ATOMIC_RELAXED, __HIP_MEMORY_SCOPE_AGENT)
#define STORE_AU(p,v) __hip_atomic_store((p), (v), __ATOMIC_RELAXED, __HIP_MEMORY_SCOPE_AGENT)

// LDS arena: one member live at a time per block (phases separated by syncs).
union SM {
    struct { float adj[NN]; float acc[SLICE]; float dem[SLICE]; u64 edges[ECAP]; } c;   // 106 KB chain
    struct { unsigned cnt[CSB * CSB]; unsigned hist[CSB]; unsigned bst[CSB + 1]; unsigned offs[CSB]; } sc;
    struct { unsigned cnt[RSB * NGRP]; unsigned hist[NGRP]; unsigned bst[NGRP + 1]; unsigned offs[NGRP]; } sr;
    struct { float img[NN]; u64 eL[2048]; } s;                                          // 48 KB scatter
};

// set-own-word + poll barrier (nblk participants). Caller syncs first.
__device__ __forceinline__ void flag_barrier_n(unsigned* fl, int idx, int tid, int nblk) {
    if (tid == 0) STORE_AU(&fl[idx], MAGIC);
    asm volatile("" ::: "memory");
    if (tid < 64) {
        for (;;) {
            unsigned f = (tid < nblk) ? LOAD_AU(&fl[tid]) : MAGIC;
            if (__all(f == MAGIC)) break;
            __builtin_amdgcn_s_sleep(2);
        }
    }
    asm volatile("" ::: "memory");
    __syncthreads();
}

// passive wait for nblk words (no own store). SLP: s_sleep ticks (64cyc each),
// compile-time literal (gfx950 requirement).
template <int SLP>
__device__ __forceinline__ void wait_flags_n(unsigned* fl, int tid, int nblk) {
    if (tid < 64) {
        for (;;) {
            unsigned f = (tid < nblk) ? LOAD_AU(&fl[tid]) : MAGIC;
            if (__all(f == MAGIC)) break;
            __builtin_amdgcn_s_sleep(SLP);
        }
    }
    asm volatile("" ::: "memory");
    __syncthreads();
}

__global__ void __launch_bounds__(THREADS) mega(
        const float* __restrict__ values, const float* __restrict__ dem,
        const int* __restrict__ rows, const int* __restrict__ cols,
        u64* __restrict__ se,        // EE col-sorted: (row13|coff8<<13)|v<<32
        u64* __restrict__ se2,       // EE row-sorted: (col13|rl5<<13)|v<<32
        u64* __restrict__ adjp,      // 9*HN (slots 1..8)
        float* __restrict__ adj9f,   // NN (= A10)
        unsigned* __restrict__ cnt,  // CSB*CSB
        unsigned* __restrict__ cnt2, // RSB*NGRP
        unsigned* __restrict__ gstart,   // NGRP+1
        unsigned* __restrict__ flagsC, unsigned* __restrict__ flagsR,
        unsigned* __restrict__ flagsE, unsigned* __restrict__ flagsR2,
        unsigned* __restrict__ flagsK, unsigned* __restrict__ done,
        float* __restrict__ out) {
    __shared__ SM sm;
    __shared__ float a9[GROWS];              // scatter: my group's adj values
    const int bid = blockIdx.x, tid = threadIdx.x;

    if (bid < CSB) {
        // ============ col-sort (bucket = col>>8) ============
        if (tid < CSB) sm.sc.hist[tid] = 0;
        __syncthreads();
        const int4* c4 = (const int4*)(cols + bid * EPB);
        int4 ca = c4[2 * tid], cb = c4[2 * tid + 1];
        atomicAdd(&sm.sc.hist[ca.x >> 8], 1u);  atomicAdd(&sm.sc.hist[ca.y >> 8], 1u);
        atomicAdd(&sm.sc.hist[ca.z >> 8], 1u);  atomicAdd(&sm.sc.hist[ca.w >> 8], 1u);
        atomicAdd(&sm.sc.hist[cb.x >> 8], 1u);  atomicAdd(&sm.sc.hist[cb.y >> 8], 1u);
        atomicAdd(&sm.sc.hist[cb.z >> 8], 1u);  atomicAdd(&sm.sc.hist[cb.w >> 8], 1u);
        __syncthreads();
        if (tid < CSB) STORE_AU(&cnt[bid * CSB + tid], sm.sc.hist[tid]);
        __syncthreads();
        flag_barrier_n(flagsC, bid, tid, CSB);

        sm.sc.cnt[tid] = LOAD_AU(&cnt[tid]);         // CSB*CSB == THREADS
        __syncthreads();
        if (tid < CSB) {
            unsigned t = 0;
            for (int b = 0; b < CSB; ++b) t += sm.sc.cnt[b * CSB + tid];
            sm.sc.hist[tid] = t;
        }
        __syncthreads();
        if (tid == 0) {
            unsigned run = 0;
            for (int k = 0; k < CSB; ++k) { sm.sc.bst[k] = run; run += sm.sc.hist[k]; }
            sm.sc.bst[CSB] = run;
        }
        __syncthreads();
        if (tid < CSB) {
            unsigned off = sm.sc.bst[tid];
            for (int b = 0; b < bid; ++b) off += sm.sc.cnt[b * CSB + tid];
            sm.sc.offs[tid] = off;
        }
        __syncthreads();
        const int bs = (int)sm.sc.bst[bid];          // keep range in regs
        const int be = (int)sm.sc.bst[bid + 1];

        {   // scatter my chunk into bucket-sorted packed array (agent stores)
            const int4*   r4 = (const int4*)(rows + bid * EPB);
            const float4* v4 = (const float4*)(values + bid * EPB);
            int4 ra = r4[2 * tid], rb = r4[2 * tid + 1];
            float4 va = v4[2 * tid], vb = v4[2 * tid + 1];
            #define PUSHC(R, C, V) do {                                        \
                int k_ = (C) >> 8;                                             \
                unsigned dst_ = atomicAdd(&sm.sc.offs[k_], 1u);                \
                u64 w_ = (unsigned)((R) | (((C) & 255) << 13))                 \
                       | ((u64)__float_as_uint(V) << 32);                      \
                STORE_AU(&se[dst_], w_);                                       \
            } while (0)
            PUSHC(ra.x, ca.x, va.x);  PUSHC(ra.y, ca.y, va.y);
            PUSHC(ra.z, ca.z, va.z);  PUSHC(ra.w, ca.w, va.w);
            PUSHC(rb.x, cb.x, vb.x);  PUSHC(rb.y, cb.y, vb.y);
            PUSHC(rb.z, cb.z, vb.z);  PUSHC(rb.w, cb.w, vb.w);
            #undef PUSHC
        }
        __syncthreads();                          // drain se stores
        flag_barrier_n(flagsE, bid, tid, CSB);    // all buckets complete

        // ============ chain: my bucket's edges -> LDS, 9 stages ============
        const int ne = be - bs;
        const int nc = ne < ECAP ? ne : ECAP;
        for (int i = tid; i < nc; i += THREADS) sm.c.edges[i] = LOAD_AU(&se[bs + i]);
        if (tid < SLICE) sm.c.dem[tid] = dem[bid * SLICE + tid];

        for (int s = 1; s <= 9; ++s) {
            if (s == 1) {                         // A1 = relu(0 - d)
                #pragma unroll
                for (int j = 0; j < NN / THREADS; ++j) {
                    int c = tid + j * THREADS;
                    sm.c.adj[c] = fmaxf(-dem[c], 0.f);
                }
            } else {                              // A_s published at stage s-1
                const u64* ap = adjp + (size_t)(s - 1) * HN;
                #pragma unroll
                for (int j = 0; j < HN / THREADS; ++j) {
                    int i = tid + j * THREADS;
                    u64 w = LOAD_AU(&ap[i]);
                    sm.c.adj[2 * i]     = __uint_as_float((unsigned)w);
                    sm.c.adj[2 * i + 1] = __uint_as_float((unsigned)(w >> 32));
                }
            }
            if (tid < SLICE) sm.c.acc[tid] = 0.f;
            __syncthreads();

            for (int i = tid; i < nc; i += THREADS) {        // pure-LDS pass
                u64 w = sm.c.edges[i];
                unsigned m = (unsigned)w;
                float v = __uint_as_float((unsigned)(w >> 32));
                atomicAdd(&sm.c.acc[(m >> 13) & 255], v * sm.c.adj[m & (NN - 1)]);
            }
            for (int i = bs + ECAP + tid; i < be; i += THREADS) {   // ~never
                u64 w = LOAD_AU(&se[i]);
                unsigned m = (unsigned)w;
                float v = __uint_as_float((unsigned)(w >> 32));
                atomicAdd(&sm.c.acc[(m >> 13) & 255], v * sm.c.adj[m & (NN - 1)]);
            }
            __syncthreads();

            if (s < 9) {
                if (tid < HSLICE) {               // fused relu+pack+publish 1KB
                    float lo = fmaxf(sm.c.acc[2 * tid]     - sm.c.dem[2 * tid],     0.f);
                    float hi = fmaxf(sm.c.acc[2 * tid + 1] - sm.c.dem[2 * tid + 1], 0.f);
                    u64 w = ((u64)__float_as_uint(hi) << 32) | __float_as_uint(lo);
                    STORE_AU(&adjp[(size_t)s * HN + bid * HSLICE + tid], w);
                }
                __syncthreads();                  // drain publish
                flag_barrier_n(flagsK + (s - 1) * 64, bid, tid, FBLK);
            } else {
                if (tid < SLICE)
                    STORE_AU(&adj9f[bid * SLICE + tid],
                             fmaxf(sm.c.acc[tid] - sm.c.dem[tid], 0.f));
                __syncthreads();                  // drain adj9f
                flag_barrier_n(done, bid, tid, FBLK);   // ALL adj9f visible
            }
        }
        wait_flags_n<2>(flagsR2, tid, RSB);       // se2/gstart ready (long ago)
    } else if (bid < CSB + RSB) {
        // ============ row-sort (group = row>>5) ============
        const int b2 = bid - CSB;
        if (tid < NGRP) sm.sr.hist[tid] = 0;
        __syncthreads();
        const int4* r4 = (const int4*)(rows + b2 * EPB);
        int4 ra = r4[2 * tid], rb = r4[2 * tid + 1];
        atomicAdd(&sm.sr.hist[ra.x >> 5], 1u);  atomicAdd(&sm.sr.hist[ra.y >> 5], 1u);
        atomicAdd(&sm.sr.hist[ra.z >> 5], 1u);  atomicAdd(&sm.sr.hist[ra.w >> 5], 1u);
        atomicAdd(&sm.sr.hist[rb.x >> 5], 1u);  atomicAdd(&sm.sr.hist[rb.y >> 5], 1u);
        atomicAdd(&sm.sr.hist[rb.z >> 5], 1u);  atomicAdd(&sm.sr.hist[rb.w >> 5], 1u);
        __syncthreads();
        if (tid < NGRP) STORE_AU(&cnt2[b2 * NGRP + tid], sm.sr.hist[tid]);
        __syncthreads();
        flag_barrier_n(flagsR, b2, tid, RSB);

        #pragma unroll
        for (int j = 0; j < (RSB * NGRP) / THREADS; ++j)
            sm.sr.cnt[tid + j * THREADS] = LOAD_AU(&cnt2[tid + j * THREADS]);
        __syncthreads();
        if (tid < NGRP) {
            unsigned t = 0;
            for (int b = 0; b < RSB; ++b) t += sm.sr.cnt[b * NGRP + tid];
            sm.sr.hist[tid] = t;
        }
        __syncthreads();
        if (tid == 0) {
            unsigned run = 0;
            for (int k = 0; k < NGRP; ++k) { sm.sr.bst[k] = run; run += sm.sr.hist[k]; }
            sm.sr.bst[NGRP] = run;
        }
        __syncthreads();
        if (tid < NGRP) {
            unsigned off = sm.sr.bst[tid];
            for (int b = 0; b < b2; ++b) off += sm.sr.cnt[b * NGRP + tid];
            sm.sr.offs[tid] = off;
        }
        __syncthreads();
        if (b2 == 0 && tid <= NGRP) STORE_AU(&gstart[tid], sm.sr.bst[tid]);

        {
            const int4*   c4 = (const int4*)(cols + b2 * EPB);
            const float4* v4 = (const float4*)(values + b2 * EPB);
            int4 ca = c4[2 * tid], cb = c4[2 * tid + 1];
            float4 va = v4[2 * tid], vb = v4[2 * tid + 1];
            #define PUSHR(R, C, V) do {                                        \
                int g_ = (R) >> 5;                                             \
                unsigned dst_ = atomicAdd(&sm.sr.offs[g_], 1u);                \
                u64 w_ = (unsigned)((C) | (((R) & 31) << 13))                  \
                       | ((u64)__float_as_uint(V) << 32);                      \
                STORE_AU(&se2[dst_], w_);                                      \
            } while (0)
            PUSHR(ra.x, ca.x, va.x);  PUSHR(ra.y, ca.y, va.y);
            PUSHR(ra.z, ca.z, va.z);  PUSHR(ra.w, ca.w, va.w);
            PUSHR(rb.x, cb.x, vb.x);  PUSHR(rb.y, cb.y, vb.y);
            PUSHR(rb.z, cb.z, vb.z);  PUSHR(rb.w, cb.w, vb.w);
            #undef PUSHR
        }
        __syncthreads();                          // drain se2/gstart stores
        if (tid == 0) STORE_AU(&flagsR2[b2], MAGIC);
        asm volatile("" ::: "memory");
        wait_flags_n<4>(flagsR2, tid, RSB);       // ALL se2/gstart visible
        wait_flags_n<32>(done, tid, FBLK);        // ~40-60us: sleep-poll
    } else {
        // ============ parked blocks: sleep-poll prerequisites ============
        wait_flags_n<32>(flagsR2, tid, RSB);
        wait_flags_n<32>(done, tid, FBLK);
    }

    // ==== scatter: every block streams row-group `bid` (all prereqs seen:
    // ==== flagsR2 all 32 => se2+gstart; done all 32 => adj9f) ====
    {
        const int g = bid;
        const unsigned gs = LOAD_AU(&gstart[g]), ge = LOAD_AU(&gstart[g + 1]);
        const unsigned n = ge - gs;
        const unsigned ncp = n < 2048u ? n : 2048u;
        if (tid < GROWS) a9[tid] = LOAD_AU(&adj9f[g * GROWS + tid]);
        __syncthreads();

        for (unsigned i = tid; i < ncp; i += THREADS) {   // premultiply
            u64 w = LOAD_AU(&se2[gs + i]);
            unsigned m = (unsigned)w;
            float v = __uint_as_float((unsigned)(w >> 32));
            sm.s.eL[i] = (u64)m | ((u64)__float_as_uint(v * a9[(m >> 13) & 31]) << 32);
        }
        __syncthreads();

        for (int r = 0; r < GROWS; ++r) {
            #pragma unroll
            for (int k = 0; k < NN / THREADS; ++k) sm.s.img[tid + k * THREADS] = 0.f;
            __syncthreads();
            for (unsigned i = tid; i < ncp; i += THREADS) {
                u64 w = sm.s.eL[i];
                unsigned m = (unsigned)w;
                if (((m >> 13) & 31) == (unsigned)r)
                    atomicAdd(&sm.s.img[m & (NN - 1)],
                              __uint_as_float((unsigned)(w >> 32)));
            }
            for (unsigned i = 2048u + tid; i < n; i += THREADS) {   // ~never
                u64 w = LOAD_AU(&se2[gs + i]);
                unsigned m = (unsigned)w;
                if (((m >> 13) & 31) == (unsigned)r)
                    atomicAdd(&sm.s.img[m & (NN - 1)],
                              __uint_as_float((unsigned)(w >> 32)) * a9[r]);
            }
            __syncthreads();
            float4* o4 = (float4*)(out + (size_t)(g * GROWS + r) * NN);
            const float4* i4 = (const float4*)sm.s.img;
            o4[tid]        = i4[tid];
            o4[tid + 1024] = i4[tid + 1024];
            __syncthreads();
        }
    }
}

extern "C" void kernel_launch(void* const* d_in, const int* in_sizes, int n_in,
                              void* d_out, int out_size, void* d_ws, size_t ws_size,
                              hipStream_t stream) {
    const float* values = (const float*)d_in[0];
    const float* dem    = (const float*)d_in[1];
    const int*   rows   = (const int*)d_in[2];
    const int*   cols   = (const int*)d_in[3];
    float* out = (float*)d_out;

    u64*      se      = (u64*)d_ws;                       // 2 MB
    u64*      se2     = se + (size_t)EE;                  // 2 MB
    u64*      adjp    = se2 + (size_t)EE;                 // 288 KB
    float*    adj9f   = (float*)(adjp + 9L * HN);         // 32 KB
    unsigned* cnt     = (unsigned*)(adj9f + NN);          // 4 KB
    unsigned* cnt2    = cnt + CSB * CSB;                  // 32 KB
    unsigned* gstart  = cnt2 + RSB * NGRP;                // 1 KB (+pad)
    unsigned* flagsC  = gstart + 320;
    unsigned* flagsR  = flagsC + 64;
    unsigned* flagsE  = flagsR + 64;
    unsigned* flagsR2 = flagsE + 64;
    unsigned* done    = flagsR2 + 64;
    unsigned* flagsK  = done + 64;                        // 8*64

    mega<<<NBLK, THREADS, 0, stream>>>(
        values, dem, rows, cols, se, se2, adjp, adj9f, cnt, cnt2, gstart,
        flagsC, flagsR, flagsE, flagsR2, flagsK, done, out);
}

// Round 9
// 343.338 us; speedup vs baseline: 2.2417x; 1.1746x over previous
//
#include <hip/hip_runtime.h>

// SparseMinCostFlow — SINGLE mega-dispatch: sorts ∥ 256-wide chain → streamed scatter.
// N=8192, E=262144, 10 flow iters, dense NxN fp32 out (256 MB).
//
// r8 accounting: total 403 = harness fills (~204, fixed) + mega 199. Mega's
// floor is ~45us (256MB out write); ~150us was latency/sync:
//  - chain on 32 blocks: 9 x (32KB adj MALL reload + barrier) on 32 CUs
//  - scatter: __syncthreads drains vmcnt(0) every row -> serialized stores
// r9 restructure:
//  - chain on ALL 256 blocks: block b owns cols [b*32,(b+1)*32), its ~1024
//    edges live in 2 VGPRs; per stage: 1-2 adj GATHERS (agent/MALL) + 32-col
//    LDS acc + 32-float publish + one 256-party flag barrier. No adj streaming.
//  - scatter: img double-buffer + raw s_barrier (lgkmcnt(0) only, no vmcnt
//    drain) -> output stores stream at HBM BW across rows.
//  - sorts: 256 col-buckets (col>>5) and 256 row-groups (row>>5).
// Uniform pre-scatter prereqs for ALL blocks (r7 tripwire lesson): stage-9
// 256-party barrier (adj9f) + all-32 flagsR2 (se2/gstart).
// All cross-block data agent-scope (L2-bypass; ws is poison-filled via plain
// stores each iter => plain reads could hit stale 0xAA in L2). Grid=256=#CUs,
// LDS padded >80KB => 1 block/CU, all co-resident.

#define NN 8192
#define EE 262144
#define THREADS 1024
#define SORTB 32                 // blocks per sort team
#define EPB (EE / SORTB)         // 8192 edges per sort block
#define NB 256                   // buckets = groups = chain blocks
#define CPB (NN / NB)            // 32 cols per chain block
#define GROWS 32                 // rows per scatter group
#define NBLK 256
#define MAGIC 0x5CA1AB1Eu        // != 0xAAAAAAAA ws poison, != 0

typedef unsigned long long u64;

#define LOAD_AU(p)    __hip_atomic_load((p),  __ATOMIC_RELAXED, __HIP_MEMORY_SCOPE_AGENT)
#define STORE_AU(p,v) __hip_atomic_store((p), (v), __ATOMIC_RELAXED, __HIP_MEMORY_SCOPE_AGENT)

// raw barrier: drain DS only (NOT vmcnt) — lets global stores stream across rows
#define LBAR() do { asm volatile("s_waitcnt lgkmcnt(0)" ::: "memory"); \
                    __builtin_amdgcn_s_barrier(); \
                    __builtin_amdgcn_sched_barrier(0); } while (0)

// LDS arena: one member live at a time (phases separated by barriers).
union SM {
    struct { unsigned cnt[SORTB * NB]; unsigned hist[NB]; unsigned bst[NB + 1]; unsigned offs[NB]; } so; // ~34 KB
    struct { float acc[CPB]; float dem[CPB]; } c;                                  // 256 B
    struct { float img[2 * NN]; u64 eL[2048]; } s;                                 // 80 KB
    char pad[90112];                                                               // force 1 block/CU
};

// 32-party: set own word + poll (caller __syncthreads first: vmcnt drain).
__device__ __forceinline__ void flag_barrier_n(unsigned* fl, int idx, int tid, int nblk) {
    if (tid == 0) STORE_AU(&fl[idx], MAGIC);
    asm volatile("" ::: "memory");
    if (tid < 64) {
        for (;;) {
            unsigned f = (tid < nblk) ? LOAD_AU(&fl[tid]) : MAGIC;
            if (__all(f == MAGIC)) break;
            __builtin_amdgcn_s_sleep(2);
        }
    }
    asm volatile("" ::: "memory");
    __syncthreads();
}

// 256-party: set own word + poll 4 words/lane.
__device__ __forceinline__ void flag_barrier_256(unsigned* fl, int idx, int tid) {
    if (tid == 0) STORE_AU(&fl[idx], MAGIC);
    asm volatile("" ::: "memory");
    if (tid < 64) {
        for (;;) {
            unsigned a = LOAD_AU(&fl[tid]);
            unsigned b = LOAD_AU(&fl[tid + 64]);
            unsigned c = LOAD_AU(&fl[tid + 128]);
            unsigned d = LOAD_AU(&fl[tid + 192]);
            if (__all(a == MAGIC && b == MAGIC && c == MAGIC && d == MAGIC)) break;
            __builtin_amdgcn_s_sleep(2);
        }
    }
    asm volatile("" ::: "memory");
    __syncthreads();
}

// passive wait on nblk(<=64) words. SLP: s_sleep ticks, compile-time literal.
template <int SLP>
__device__ __forceinline__ void wait_flags_n(unsigned* fl, int tid, int nblk) {
    if (tid < 64) {
        for (;;) {
            unsigned f = (tid < nblk) ? LOAD_AU(&fl[tid]) : MAGIC;
            if (__all(f == MAGIC)) break;
            __builtin_amdgcn_s_sleep(SLP);
        }
    }
    asm volatile("" ::: "memory");
    __syncthreads();
}

__global__ void __launch_bounds__(THREADS) mega(
        const float* __restrict__ values, const float* __restrict__ dem,
        const int* __restrict__ rows, const int* __restrict__ cols,
        u64* __restrict__ se,        // EE col-sorted: row13 | coff5<<13 | v<<32
        u64* __restrict__ se2,       // EE row-sorted: col13 | rl5<<13  | v<<32
        float* __restrict__ adjF,    // 9*NN floats (slots 1..8)
        float* __restrict__ adj9f,   // NN floats (= A10)
        unsigned* __restrict__ cnt,  // SORTB*NB
        unsigned* __restrict__ cnt2, // SORTB*NB
        unsigned* __restrict__ bstart,   // NB+1
        unsigned* __restrict__ gstart,   // NB+1
        unsigned* __restrict__ flagsC, unsigned* __restrict__ flagsR,
        unsigned* __restrict__ flagsE, unsigned* __restrict__ flagsR2,
        unsigned* __restrict__ flagsK,   // 9*NB
        float* __restrict__ out) {
    __shared__ SM sm;
    __shared__ float a9[GROWS];
    const int bid = blockIdx.x, tid = threadIdx.x;

    if (bid < SORTB) {
        // ============ col-sort team: bucket = col>>5 (256 buckets) ============
        if (tid < NB) sm.so.hist[tid] = 0;
        __syncthreads();
        const int4* c4 = (const int4*)(cols + bid * EPB);
        int4 ca = c4[2 * tid], cb = c4[2 * tid + 1];
        atomicAdd(&sm.so.hist[ca.x >> 5], 1u);  atomicAdd(&sm.so.hist[ca.y >> 5], 1u);
        atomicAdd(&sm.so.hist[ca.z >> 5], 1u);  atomicAdd(&sm.so.hist[ca.w >> 5], 1u);
        atomicAdd(&sm.so.hist[cb.x >> 5], 1u);  atomicAdd(&sm.so.hist[cb.y >> 5], 1u);
        atomicAdd(&sm.so.hist[cb.z >> 5], 1u);  atomicAdd(&sm.so.hist[cb.w >> 5], 1u);
        __syncthreads();
        if (tid < NB) STORE_AU(&cnt[bid * NB + tid], sm.so.hist[tid]);
        __syncthreads();                              // drain cnt
        flag_barrier_n(flagsC, bid, tid, SORTB);

        #pragma unroll
        for (int j = 0; j < (SORTB * NB) / THREADS; ++j)
            sm.so.cnt[tid + j * THREADS] = LOAD_AU(&cnt[tid + j * THREADS]);
        __syncthreads();
        if (tid < NB) {
            unsigned t = 0;
            for (int b = 0; b < SORTB; ++b) t += sm.so.cnt[b * NB + tid];
            sm.so.hist[tid] = t;
        }
        __syncthreads();
        if (tid == 0) {
            unsigned run = 0;
            for (int k = 0; k < NB; ++k) { sm.so.bst[k] = run; run += sm.so.hist[k]; }
            sm.so.bst[NB] = run;
        }
        __syncthreads();
        if (tid < NB) {
            unsigned off = sm.so.bst[tid];
            for (int b = 0; b < bid; ++b) off += sm.so.cnt[b * NB + tid];
            sm.so.offs[tid] = off;
        }
        if (bid == 0 && tid <= NB) STORE_AU(&bstart[tid], sm.so.bst[tid]);
        __syncthreads();

        {   // push: meta = row | (col&31)<<13, value hi32
            const int4*   r4 = (const int4*)(rows + bid * EPB);
            const float4* v4 = (const float4*)(values + bid * EPB);
            int4 ra = r4[2 * tid], rb = r4[2 * tid + 1];
            float4 va = v4[2 * tid], vb = v4[2 * tid + 1];
            #define PUSHC(R, C, V) do {                                        \
                unsigned dst_ = atomicAdd(&sm.so.offs[(C) >> 5], 1u);          \
                u64 w_ = (unsigned)((R) | (((C) & 31) << 13))                  \
                       | ((u64)__float_as_uint(V) << 32);                      \
                STORE_AU(&se[dst_], w_);                                       \
            } while (0)
            PUSHC(ra.x, ca.x, va.x);  PUSHC(ra.y, ca.y, va.y);
            PUSHC(ra.z, ca.z, va.z);  PUSHC(ra.w, ca.w, va.w);
            PUSHC(rb.x, cb.x, vb.x);  PUSHC(rb.y, cb.y, vb.y);
            PUSHC(rb.z, cb.z, vb.z);  PUSHC(rb.w, cb.w, vb.w);
            #undef PUSHC
        }
        __syncthreads();                              // drain se + bstart
        flag_barrier_n(flagsE, bid, tid, SORTB);      // col-sort complete
    } else if (bid < 2 * SORTB) {
        // ============ row-sort team: group = row>>5 (256 groups) ============
        const int b2 = bid - SORTB;
        if (tid < NB) sm.so.hist[tid] = 0;
        __syncthreads();
        const int4* r4 = (const int4*)(rows + b2 * EPB);
        int4 ra = r4[2 * tid], rb = r4[2 * tid + 1];
        atomicAdd(&sm.so.hist[ra.x >> 5], 1u);  atomicAdd(&sm.so.hist[ra.y >> 5], 1u);
        atomicAdd(&sm.so.hist[ra.z >> 5], 1u);  atomicAdd(&sm.so.hist[ra.w >> 5], 1u);
        atomicAdd(&sm.so.hist[rb.x >> 5], 1u);  atomicAdd(&sm.so.hist[rb.y >> 5], 1u);
        atomicAdd(&sm.so.hist[rb.z >> 5], 1u);  atomicAdd(&sm.so.hist[rb.w >> 5], 1u);
        __syncthreads();
        if (tid < NB) STORE_AU(&cnt2[b2 * NB + tid], sm.so.hist[tid]);
        __syncthreads();
        flag_barrier_n(flagsR, b2, tid, SORTB);

        #pragma unroll
        for (int j = 0; j < (SORTB * NB) / THREADS; ++j)
            sm.so.cnt[tid + j * THREADS] = LOAD_AU(&cnt2[tid + j * THREADS]);
        __syncthreads();
        if (tid < NB) {
            unsigned t = 0;
            for (int b = 0; b < SORTB; ++b) t += sm.so.cnt[b * NB + tid];
            sm.so.hist[tid] = t;
        }
        __syncthreads();
        if (tid == 0) {
            unsigned run = 0;
            for (int k = 0; k < NB; ++k) { sm.so.bst[k] = run; run += sm.so.hist[k]; }
            sm.so.bst[NB] = run;
        }
        __syncthreads();
        if (tid < NB) {
            unsigned off = sm.so.bst[tid];
            for (int b = 0; b < b2; ++b) off += sm.so.cnt[b * NB + tid];
            sm.so.offs[tid] = off;
        }
        if (b2 == 0 && tid <= NB) STORE_AU(&gstart[tid], sm.so.bst[tid]);
        __syncthreads();

        {   // push: meta = col | (row&31)<<13, value hi32
            const int4*   c4 = (const int4*)(cols + b2 * EPB);
            const float4* v4 = (const float4*)(values + b2 * EPB);
            int4 ca = c4[2 * tid], cb = c4[2 * tid + 1];
            float4 va = v4[2 * tid], vb = v4[2 * tid + 1];
            #define PUSHR(R, C, V) do {                                        \
                unsigned dst_ = atomicAdd(&sm.so.offs[(R) >> 5], 1u);          \
                u64 w_ = (unsigned)((C) | (((R) & 31) << 13))                  \
                       | ((u64)__float_as_uint(V) << 32);                      \
                STORE_AU(&se2[dst_], w_);                                      \
            } while (0)
            PUSHR(ra.x, ca.x, va.x);  PUSHR(ra.y, ca.y, va.y);
            PUSHR(ra.z, ca.z, va.z);  PUSHR(ra.w, ca.w, va.w);
            PUSHR(rb.x, cb.x, vb.x);  PUSHR(rb.y, cb.y, vb.y);
            PUSHR(rb.z, cb.z, vb.z);  PUSHR(rb.w, cb.w, vb.w);
            #undef PUSHR
        }
        __syncthreads();                              // drain se2 + gstart
        if (tid == 0) STORE_AU(&flagsR2[b2], MAGIC);
        asm volatile("" ::: "memory");
        wait_flags_n<4>(flagsE, tid, SORTB);          // then join the chain
    } else {
        // ============ parked until col-sort done ============
        wait_flags_n<8>(flagsE, tid, SORTB);
    }

    // ================= chain: ALL 256 blocks, block owns bucket `bid` =======
    const int bs = (int)LOAD_AU(&bstart[bid]);
    const int be = (int)LOAD_AU(&bstart[bid + 1]);
    const int ne = be - bs;
    u64 e0 = 0, e1 = 0;                               // ~1024 edges -> 2 regs
    if (tid < ne)           e0 = LOAD_AU(&se[bs + tid]);
    if (THREADS + tid < ne) e1 = LOAD_AU(&se[bs + THREADS + tid]);
    if (tid < CPB) sm.c.dem[tid] = dem[bid * CPB + tid];

    for (int s = 1; s <= 9; ++s) {
        if (tid < CPB) sm.c.acc[tid] = 0.f;
        __syncthreads();

        #define EDGE(W) do {                                                   \
            unsigned m_ = (unsigned)(W);                                       \
            float v_ = __uint_as_float((unsigned)((W) >> 32));                 \
            int r_ = m_ & (NN - 1);                                            \
            float a_ = (s == 1) ? fmaxf(-dem[r_], 0.f)                         \
                                : LOAD_AU(&adjF[(size_t)(s - 1) * NN + r_]);   \
            atomicAdd(&sm.c.acc[(m_ >> 13) & 31], v_ * a_);                    \
        } while (0)
        if (tid < ne)           EDGE(e0);
        if (THREADS + tid < ne) EDGE(e1);
        for (int i = bs + 2 * THREADS + tid; i < be; i += THREADS) {  // ~never
            u64 w = LOAD_AU(&se[i]);
            EDGE(w);
        }
        #undef EDGE
        __syncthreads();

        if (tid < CPB) {
            float r = fmaxf(sm.c.acc[tid] - sm.c.dem[tid], 0.f);
            if (s < 9) STORE_AU(&adjF[(size_t)s * NN + bid * CPB + tid], r);
            else       STORE_AU(&adj9f[bid * CPB + tid], r);
        }
        __syncthreads();                              // drain publish
        flag_barrier_256(flagsK + (s - 1) * NB, bid, tid);
    }
    // stage-9 barrier above == adj9f all visible. Uniform last prereq:
    wait_flags_n<2>(flagsR2, tid, SORTB);             // se2/gstart (long ready)

    // ======= scatter: block streams row-group `bid`, img double-buffered ====
    {
        const int g = bid;
        const unsigned gs = LOAD_AU(&gstart[g]), ge = LOAD_AU(&gstart[g + 1]);
        const unsigned n = ge - gs;
        const unsigned ncp = n < 2048u ? n : 2048u;
        if (tid < GROWS) a9[tid] = LOAD_AU(&adj9f[g * GROWS + tid]);
        __syncthreads();                              // a9 + LDS transition

        for (unsigned i = tid; i < ncp; i += THREADS) {   // premultiply
            u64 w = LOAD_AU(&se2[gs + i]);
            unsigned m = (unsigned)w;
            float v = __uint_as_float((unsigned)(w >> 32));
            sm.s.eL[i] = (u64)m | ((u64)__float_as_uint(v * a9[(m >> 13) & 31]) << 32);
        }
        __syncthreads();

        const float4 z4 = make_float4(0.f, 0.f, 0.f, 0.f);
        for (int r = 0; r < GROWS; ++r) {
            float* im = sm.s.img + (r & 1) * NN;
            ((float4*)im)[tid]        = z4;           // zero 32KB image
            ((float4*)im)[tid + 1024] = z4;
            LBAR();
            for (unsigned i = tid; i < ncp; i += THREADS) {
                u64 w = sm.s.eL[i];
                unsigned m = (unsigned)w;
                if (((m >> 13) & 31) == (unsigned)r)
                    atomicAdd(&im[m & (NN - 1)], __uint_as_float((unsigned)(w >> 32)));
            }
            for (unsigned i = 2048u + tid; i < n; i += THREADS) {   // ~never
                u64 w = LOAD_AU(&se2[gs + i]);
                unsigned m = (unsigned)w;
                if (((m >> 13) & 31) == (unsigned)r)
                    atomicAdd(&im[m & (NN - 1)],
                              __uint_as_float((unsigned)(w >> 32)) * a9[r]);
            }
            LBAR();
            float4 w0 = ((const float4*)im)[tid];     // ds_read, lgkm-waited
            float4 w1 = ((const float4*)im)[tid + 1024];
            float4* o4 = (float4*)(out + (size_t)(g * GROWS + r) * NN);
            o4[tid]        = w0;                      // stores stream (no drain)
            o4[tid + 1024] = w1;
        }
    }
}

extern "C" void kernel_launch(void* const* d_in, const int* in_sizes, int n_in,
                              void* d_out, int out_size, void* d_ws, size_t ws_size,
                              hipStream_t stream) {
    const float* values = (const float*)d_in[0];
    const float* dem    = (const float*)d_in[1];
    const int*   rows   = (const int*)d_in[2];
    const int*   cols   = (const int*)d_in[3];
    float* out = (float*)d_out;

    u64*      se      = (u64*)d_ws;                       // 2 MB
    u64*      se2     = se + (size_t)EE;                  // 2 MB
    float*    adjF    = (float*)(se2 + (size_t)EE);       // 288 KB
    float*    adj9f   = adjF + 9L * NN;                   // 32 KB
    unsigned* cnt     = (unsigned*)(adj9f + NN);          // 32 KB
    unsigned* cnt2    = cnt + SORTB * NB;                 // 32 KB
    unsigned* bstart  = cnt2 + SORTB * NB;                // 257 (+pad)
    unsigned* gstart  = bstart + 320;                     // 257 (+pad)
    unsigned* flagsC  = gstart + 320;
    unsigned* flagsR  = flagsC + 64;
    unsigned* flagsE  = flagsR + 64;
    unsigned* flagsR2 = flagsE + 64;
    unsigned* flagsK  = flagsR2 + 64;                     // 9*256

    mega<<<NBLK, THREADS, 0, stream>>>(
        values, dem, rows, cols, se, se2, adjF, adj9f, cnt, cnt2,
        bstart, gstart, flagsC, flagsR, flagsE, flagsR2, flagsK, out);
}